// Round 4
// baseline (235.612 us; speedup 1.0000x reference)
//
#include <hip/hip_runtime.h>

#define IMG_H 512
#define IMG_W 512
#define NPLANES 48
#define TX 64          // tile width
#define TY 16          // rows per half-tile; each block processes two halves (32 rows)
#define VW 74          // staged cols = TX + 10
#define VSTRIDE 75     // odd stride -> 2-way (free) bank pattern in H-pass
#define NF 5
#define BLOCK 256

// Gaussian window for WINDOW=11, sigma=1.5, normalized. Computed offline in
// double precision (exp(-(i-5)^2/4.5)/sum); rel err ~1e-8 vs the reference's
// float64->float32 window — far below the 2.6e-4 threshold.
static constexpr float WG[11] = {
    0.0010283804f, 0.0075987582f, 0.0360007723f, 0.1093606901f,
    0.2130055377f, 0.2660117259f, 0.2130055377f, 0.1093606901f,
    0.0360007723f, 0.0075987582f, 0.0010283804f
};

// Vertical pass: task = (column c of 74, 4-row group r0). 296 tasks.
template <bool BORDER>
__device__ __forceinline__ void vpass(const float* __restrict__ i1,
                                      const float* __restrict__ i2,
                                      float* __restrict__ vs,
                                      int x0, int y0, int tid) {
    for (int t = tid; t < VW * (TY / 4); t += BLOCK) {
        int rq = t / VW;
        int c  = t - rq * VW;
        int r0 = rq << 2;
        int gx = x0 - 5 + c;
        int gy0 = y0 + r0 - 5;
        float acc[NF][4];
        #pragma unroll
        for (int f = 0; f < NF; ++f)
            #pragma unroll
            for (int j = 0; j < 4; ++j) acc[f][j] = 0.f;

        const float* p1 = i1 + (ptrdiff_t)gy0 * IMG_W + gx;
        const float* p2 = i2 + (ptrdiff_t)gy0 * IMG_W + gx;
        #pragma unroll
        for (int i = 0; i < 14; ++i) {
            float a, b;
            if (BORDER) {
                int gy = gy0 + i;
                bool ok = ((unsigned)gy < IMG_H) & ((unsigned)gx < IMG_W);
                int g = ok ? gy * IMG_W + gx : 0;
                a = i1[g]; b = i2[g];
                a = ok ? a : 0.f;
                b = ok ? b : 0.f;
            } else {
                a = p1[(ptrdiff_t)i * IMG_W];
                b = p2[(ptrdiff_t)i * IMG_W];
            }
            float aa = a * a, bb = b * b, ab = a * b;
            #pragma unroll
            for (int j = 0; j < 4; ++j) {
                int k = i - j;                    // compile-time per (i,j)
                if (k >= 0 && k < 11) {
                    acc[0][j] += WG[k] * a;
                    acc[1][j] += WG[k] * b;
                    acc[2][j] += WG[k] * aa;
                    acc[3][j] += WG[k] * bb;
                    acc[4][j] += WG[k] * ab;
                }
            }
        }
        #pragma unroll
        for (int f = 0; f < NF; ++f)
            #pragma unroll
            for (int j = 0; j < 4; ++j)
                vs[f * TY * VSTRIDE + (r0 + j) * VSTRIDE + c] = acc[f][j];
    }
}

// Horizontal pass + SSIM for exactly one task per thread: (row, col-quad).
__device__ __forceinline__ float hpass_ssim(const float* __restrict__ vs, int tid) {
    int r  = tid >> 4;
    int c0 = (tid & 15) << 2;
    float acc[NF][4];
    #pragma unroll
    for (int f = 0; f < NF; ++f) {
        const float* vp = vs + f * TY * VSTRIDE + r * VSTRIDE + c0;
        float hv[14];
        #pragma unroll
        for (int i = 0; i < 14; ++i) hv[i] = vp[i];
        #pragma unroll
        for (int j = 0; j < 4; ++j) {
            float s = 0.f;
            #pragma unroll
            for (int k = 0; k < 11; ++k) s += WG[k] * hv[k + j];
            acc[f][j] = s;
        }
    }
    float lsum = 0.f;
    #pragma unroll
    for (int j = 0; j < 4; ++j) {
        float mu1 = acc[0][j], mu2 = acc[1][j];
        float ex2 = acc[2][j], ey2 = acc[3][j], exy = acc[4][j];
        float mu1s = mu1 * mu1;
        float mu2s = mu2 * mu2;
        float mu12 = mu1 * mu2;
        float s1q = ex2 - mu1s;
        float s2q = ey2 - mu2s;
        float s12 = exy - mu12;
        float v1 = 2.f * s12 + 9e-4f;
        float v2 = s1q + s2q + 9.01e-4f;          // C2 + 1e-6
        float num = (2.f * mu12 + 1e-4f) * v1;    // C1 = 1e-4
        float den = (mu1s + mu2s + 1e-4f) * v2;
        lsum += num * __builtin_amdgcn_rcpf(den); // 1-ulp rcp, error ~1e-7
    }
    return lsum;
}

__global__ __launch_bounds__(BLOCK, 6)   // 6 waves/SIMD: 24 KB LDS -> 6 blocks/CU
void ssim_main(const float* __restrict__ img1, const float* __restrict__ img2,
               float* __restrict__ blocksums) {
    __shared__ float vs[NF * TY * VSTRIDE];   // 5*16*75*4 = 24000 B
    __shared__ float red[4];

    const int tid = threadIdx.x;
    const int x0 = blockIdx.x * TX;
    const float* i1 = img1 + (size_t)blockIdx.z * (IMG_H * IMG_W);
    const float* i2 = img2 + (size_t)blockIdx.z * (IMG_H * IMG_W);
    const bool xb = (blockIdx.x == 0) | (blockIdx.x == gridDim.x - 1);

    float lsum = 0.f;
    for (int half = 0; half < 2; ++half) {
        int y0 = blockIdx.y * 32 + half * TY;
        bool border = xb | (half == 0 ? (blockIdx.y == 0)
                                      : (blockIdx.y == gridDim.y - 1));
        if (border) vpass<true >(i1, i2, vs, x0, y0, tid);
        else        vpass<false>(i1, i2, vs, x0, y0, tid);
        __syncthreads();
        lsum += hpass_ssim(vs, tid);
        __syncthreads();   // vs reused by next half
    }

    // block reduction -> one float per block (every slot written every launch)
    #pragma unroll
    for (int off = 32; off; off >>= 1) lsum += __shfl_down(lsum, off, 64);
    if ((tid & 63) == 0) red[tid >> 6] = lsum;
    __syncthreads();
    if (tid == 0) {
        float bs = red[0] + red[1] + red[2] + red[3];
        int bid = (blockIdx.z * gridDim.y + blockIdx.y) * gridDim.x + blockIdx.x;
        blocksums[bid] = bs;
    }
}

__global__ void ssim_finalize(const float* __restrict__ bs, float* __restrict__ out, int n) {
    __shared__ double red[4];
    double s = 0.0;
    for (int i = threadIdx.x; i < n; i += BLOCK) s += (double)bs[i];
    #pragma unroll
    for (int off = 32; off; off >>= 1) s += __shfl_down(s, off, 64);
    if ((threadIdx.x & 63) == 0) red[threadIdx.x >> 6] = s;
    __syncthreads();
    if (threadIdx.x == 0)
        out[0] = (float)((red[0] + red[1] + red[2] + red[3]) / 12582912.0);
}

extern "C" void kernel_launch(void* const* d_in, const int* in_sizes, int n_in,
                              void* d_out, int out_size, void* d_ws, size_t ws_size,
                              hipStream_t stream) {
    const float* img1 = (const float*)d_in[0];
    const float* img2 = (const float*)d_in[1];
    float* out = (float*)d_out;
    float* bsums = (float*)d_ws;   // 6144 floats, all written every launch

    dim3 grid(IMG_W / TX, IMG_H / 32, NPLANES);   // 8 x 16 x 48 = 6144 blocks
    ssim_main<<<grid, BLOCK, 0, stream>>>(img1, img2, bsums);
    ssim_finalize<<<1, BLOCK, 0, stream>>>(bsums, out, 6144);
}